// Round 7
// baseline (513.576 us; speedup 1.0000x reference)
//
#include <hip/hip_runtime.h>

#define VOCAB 32000
#define EMB 64
#define NROWS 8192                // B*S
#define NSUB 500                  // VOCAB/64 subchunks of 64 cols
#define SUBPAD 512
#define NCOMPUTE 320              // 32 rowblocks x 10 chunk-groups
#define K2_BLOCKS 4096
#define NZ2 (K2_BLOCKS - NCOMPUTE)        // 3776 zero blocks in k2
#define K1_SETUP 125
#define K1_ZERO 875
#define K1_ITERS 28
#define K1_F4 (K1_ZERO * 256 * K1_ITERS)  // 6,272,000 float4 = 100.4 MB
#define TOTAL_F4 (NROWS * (VOCAB / 4))    // 65,536,000
#define K2_F4 (TOTAL_F4 - K1_F4)          // 59,264,000

typedef __attribute__((ext_vector_type(8))) short bf16x8;
typedef __attribute__((ext_vector_type(4))) float f32x4;
typedef float f4nt __attribute__((ext_vector_type(4)));

// Monotone order-preserving f32 -> u32 (equal floats -> equal keys).
__device__ __forceinline__ unsigned enc_f32(float f) {
    unsigned u = __float_as_uint(f);
    return (u & 0x80000000u) ? ~u : (u | 0x80000000u);
}
__device__ __forceinline__ float dec_f32(unsigned e) {
    unsigned u = (e & 0x80000000u) ? (e & 0x7fffffffu) : ~e;
    return __uint_as_float(u);
}
// f32 -> bf16 round-to-nearest-even (inputs Gaussian: no NaN/Inf).
__device__ __forceinline__ unsigned short f2bf(float f) {
    unsigned u = __float_as_uint(f);
    return (unsigned short)((u + 0x7fffu + ((u >> 16) & 1u)) >> 16);
}

// ---- k1: setup (125 blocks) fused with first 100.4 MB of zero-stream ----
// Setup math identical to rounds 1-6 (exact path unchanged).
__global__ __launch_bounds__(256) void k1_kernel(
    const float* __restrict__ x, const float* __restrict__ W,
    unsigned short* __restrict__ A16, unsigned short* __restrict__ WB16,
    float* __restrict__ invn, float* __restrict__ normA,
    float4* __restrict__ out4)
{
    const int bx = blockIdx.x;
    if (bx >= K1_SETUP) {
        // zero block: 28 fixed NT float4 stores/thread, covers [0, 6,272,000)
        const int zid = bx - K1_SETUP;
        const f4nt z = {0.f, 0.f, 0.f, 0.f};
        float4* p = out4 + (size_t)zid * 256 + threadIdx.x;
        #pragma unroll 4
        for (int j = 0; j < K1_ITERS; ++j)
            __builtin_nontemporal_store(z, (f4nt*)(p + (size_t)j * (K1_ZERO * 256)));
        return;
    }
    int i = bx * 256 + threadIdx.x;
    if (i < VOCAB) {
        const float4* w4 = (const float4*)(W + (size_t)i * EMB);
        float4 buf[16];
        float s = 0.f;
        #pragma unroll
        for (int q = 0; q < 16; ++q) {
            float4 w = w4[q]; buf[q] = w;
            s += w.x * w.x + w.y * w.y + w.z * w.z + w.w * w.w;
        }
        float inv = 1.0f / sqrtf(s);
        invn[i] = inv;
        ushort4* dst = (ushort4*)(WB16 + (size_t)i * EMB);
        #pragma unroll
        for (int q = 0; q < 16; ++q) {
            float4 w = buf[q];
            ushort4 u;
            u.x = f2bf(w.x * inv); u.y = f2bf(w.y * inv);
            u.z = f2bf(w.z * inv); u.w = f2bf(w.w * inv);
            dst[q] = u;
        }
    }
    if (i < NROWS) {
        const float4* a4 = (const float4*)(x + (size_t)i * EMB);
        float4 buf[16];
        float s = 0.f;
        #pragma unroll
        for (int q = 0; q < 16; ++q) {
            float4 a = a4[q]; buf[q] = a;
            s += a.x * a.x + a.y * a.y + a.z * a.z + a.w * a.w;
        }
        normA[i] = sqrtf(s);
        ushort4* dst = (ushort4*)(A16 + (size_t)i * EMB);
        #pragma unroll
        for (int q = 0; q < 16; ++q) {
            float4 a = buf[q];
            ushort4 u;
            u.x = f2bf(a.x); u.y = f2bf(a.y); u.z = f2bf(a.z); u.w = f2bf(a.w);
            dst[q] = u;
        }
    }
}

// ---- k2: 320 compute blocks (bf16 MFMA -> pval u16) sprinkled among
//      3776 zero blocks streaming the remaining 948 MB ----
// Compute block: one rowblock (256 rows), 5 contiguous chunks = 3200 cols,
// A-frags loaded once. Fragment maps (m89/m92-verified): A/B lane l:
// idx=l&15, k0=(l>>4)*8; C/D: col=l&15, row=(l>>4)*4+reg.
__global__ __launch_bounds__(256) void k2_kernel(
    const unsigned short* __restrict__ A16,
    const unsigned short* __restrict__ WB16,
    unsigned short* __restrict__ pval, float4* __restrict__ out4)
{
    const int bx = blockIdx.x;
    const bool is_compute = (bx % 12 == 0) && (bx / 12 < NCOMPUTE);

    if (!is_compute) {
        // dense zero-block id: subtract # compute blocks with index < bx
        const int nc = min(NCOMPUTE, (bx + 11) / 12);
        const int zid = bx - nc;                 // 0..3775
        const f4nt z = {0.f, 0.f, 0.f, 0.f};
        float4* base = out4 + K1_F4;
        unsigned i = (unsigned)zid * 256u + threadIdx.x;
        const unsigned stride = (unsigned)NZ2 * 256u;
        for (; i < (unsigned)K2_F4; i += stride)
            __builtin_nontemporal_store(z, (f4nt*)(base + i));
        return;
    }

    // ---- compute block ----
    const int cid = bx / 12;                     // 0..319
    const int rowblk = cid & 31, cg = cid >> 5;  // 32 rowblocks x 10 groups
    const int lane = threadIdx.x & 63, wid = threadIdx.x >> 6;
    const int lr = lane & 15, lg = lane >> 4;
    const int m0 = rowblk * 256 + wid * 64;
    const int n0 = cg * 3200;                    // 5 chunks x 640 cols

    bf16x8 a[4][2];
    #pragma unroll
    for (int r = 0; r < 4; ++r)
        #pragma unroll
        for (int kk = 0; kk < 2; ++kk)
            a[r][kk] = *(const bf16x8*)(A16 + (size_t)(m0 + r * 16 + lr) * EMB + kk * 32 + lg * 8);

    float best[4][4];
    #pragma unroll
    for (int r = 0; r < 4; ++r)
        #pragma unroll
        for (int j = 0; j < 4; ++j) best[r][j] = -3e38f;

    const unsigned short* wb = WB16 + (size_t)(n0 + lr) * EMB + lg * 8;
    bf16x8 b0 = *(const bf16x8*)(wb);
    bf16x8 b1 = *(const bf16x8*)(wb + 32);
    for (int t = 0; t < 200; ++t) {
        // prefetch next 16-col tile (cg=9,t=199 overruns 2KB into A16: harmless,
        // value discarded)
        const unsigned short* wn = wb + 16 * EMB;
        bf16x8 nb0 = *(const bf16x8*)(wn);
        bf16x8 nb1 = *(const bf16x8*)(wn + 32);
        #pragma unroll
        for (int r = 0; r < 4; ++r) {
            f32x4 acc = {0.f, 0.f, 0.f, 0.f};
            acc = __builtin_amdgcn_mfma_f32_16x16x32_bf16(a[r][0], b0, acc, 0, 0, 0);
            acc = __builtin_amdgcn_mfma_f32_16x16x32_bf16(a[r][1], b1, acc, 0, 0, 0);
            #pragma unroll
            for (int j = 0; j < 4; ++j) best[r][j] = fmaxf(best[r][j], acc[j]);
        }
        if ((t & 3) == 3) {   // 64-col subchunk boundary: reduce + u16 store
            const int sub = cg * 50 + (t >> 2);
            #pragma unroll
            for (int r = 0; r < 4; ++r)
                #pragma unroll
                for (int j = 0; j < 4; ++j) {
                    float v = best[r][j];
                    v = fmaxf(v, __shfl_xor(v, 1));
                    v = fmaxf(v, __shfl_xor(v, 2));
                    v = fmaxf(v, __shfl_xor(v, 4));
                    v = fmaxf(v, __shfl_xor(v, 8));
                    if (lr == 0)
                        pval[(size_t)(m0 + r * 16 + lg * 4 + j) * SUBPAD + sub] =
                            (unsigned short)(enc_f32(v) >> 16);
                    best[r][j] = -3e38f;
                }
        }
        b0 = nb0; b1 = nb1;
        wb = wn;
    }
}

// ---- finalize: per-row select + exact rescore + scatter (identical to r6) ----
// thr = max_approx - 0.009*|A| (2*2^-8*|A| bound + 15% slack, proven r3-r6).
// u16 compare (val+1)<<16 > thr_enc never false-prunes a truncated max.
__global__ __launch_bounds__(64) void finalize_kernel(
    const float* __restrict__ x, const float* __restrict__ W,
    const float* __restrict__ invn, const unsigned short* __restrict__ pval,
    const float* __restrict__ normA, float* __restrict__ out)
{
    const int row = blockIdx.x;
    const int lane = threadIdx.x;
    __shared__ float xs[EMB];
    xs[lane] = x[(size_t)row * EMB + lane];

    const unsigned short* pr = pval + (size_t)row * SUBPAD + lane * 8;
    ushort4 v0 = *(const ushort4*)(pr);
    ushort4 v1 = *(const ushort4*)(pr + 4);
    unsigned short vals[8] = {v0.x, v0.y, v0.z, v0.w, v1.x, v1.y, v1.z, v1.w};

    unsigned mx = 0;
    #pragma unroll
    for (int k = 0; k < 8; ++k)
        if (lane * 8 + k < NSUB) mx = mx > (unsigned)vals[k] ? mx : (unsigned)vals[k];
    #pragma unroll
    for (int off = 1; off < 64; off <<= 1) {
        unsigned o = __shfl_xor(mx, off);
        mx = mx > o ? mx : o;
    }
    float thr = dec_f32(mx << 16) - 0.009f * normA[row];
    unsigned thr_enc = enc_f32(thr);

    __syncthreads();
    const float4* xs4 = (const float4*)xs;
    unsigned long long best = 0ull;

    #pragma unroll
    for (int k = 0; k < 8; ++k) {
        int sub = lane * 8 + k;
        bool c = (sub < NSUB) && ((((unsigned)vals[k] + 1u) << 16) > thr_enc);
        unsigned long long m = __ballot(c);
        while (m) {   // ~1.4 survivors/row on average
            int src = __ffsll((long long)m) - 1;
            m &= m - 1;
            unsigned v = ((unsigned)(src * 8 + k)) * 64u + (unsigned)lane;
            const float4* w4 = (const float4*)(W + (size_t)v * EMB);
            float p0 = 0.f, p1 = 0.f, p2 = 0.f, p3 = 0.f;
            #pragma unroll
            for (int q = 0; q < 16; ++q) {
                float4 aa = xs4[q]; float4 ww = w4[q];
                p0 = fmaf(aa.x, ww.x, p0);
                p1 = fmaf(aa.y, ww.y, p1);
                p2 = fmaf(aa.z, ww.z, p2);
                p3 = fmaf(aa.w, ww.w, p3);
            }
            float s = ((p0 + p1) + (p2 + p3)) * invn[v];
            // larger sim wins; equal sim -> larger ~v = smaller v (numpy tie-break)
            unsigned long long kk =
                ((unsigned long long)enc_f32(s) << 32) | (unsigned)(~v);
            best = best > kk ? best : kk;
        }
    }
    #pragma unroll
    for (int off = 1; off < 64; off <<= 1) {
        unsigned long long o = __shfl_xor(best, off);
        best = best > o ? best : o;
    }
    if (lane == 0)
        out[(size_t)row * VOCAB + (size_t)(unsigned)(~(unsigned)best)] = 1.0f;
}

extern "C" void kernel_launch(void* const* d_in, const int* in_sizes, int n_in,
                              void* d_out, int out_size, void* d_ws, size_t ws_size,
                              hipStream_t stream) {
    const float* x = (const float*)d_in[0];   // [2,4096,64]
    const float* W = (const float*)d_in[1];   // [32000,64]
    float* out = (float*)d_out;

    char* ws = (char*)d_ws;
    unsigned short* WB16 = (unsigned short*)(ws);                 // 4,096,000
    unsigned short* A16  = (unsigned short*)(ws + 4096000);       // 1,048,576
    float* invn          = (float*)(ws + 5144576);                //   128,000
    float* normA         = (float*)(ws + 5272576);                //    32,768
    unsigned short* pval = (unsigned short*)(ws + 5305344);       // 8,388,608
    // total ws use: 13,693,952 B

    k1_kernel<<<dim3(K1_SETUP + K1_ZERO), dim3(256), 0, stream>>>(
        x, W, A16, WB16, invn, normA, (float4*)out);

    k2_kernel<<<dim3(K2_BLOCKS), dim3(256), 0, stream>>>(
        A16, WB16, pval, (float4*)out);

    finalize_kernel<<<dim3(NROWS), dim3(64), 0, stream>>>(
        x, W, invn, pval, normA, out);
}

// Round 8
// 238.618 us; speedup vs baseline: 2.1523x; 2.1523x over previous
//
#include <hip/hip_runtime.h>

#define VOCAB 32000
#define EMB 64
#define NROWS 8192                // B*S
#define NSUB 500                  // VOCAB/64 subchunks of 64 cols
#define SUBPAD 512
#define PAT 57                    // per 57 blocks: 25 compute + 32 zero
#define K2_BLOCKS 3648            // 64*57 -> 1600 compute + 2048 zero
#define NZ2 2048
#define K1_SETUP 125
#define K1_ZERO 875
#define K1_ITERS 28
#define K1_F4 (K1_ZERO * 256 * K1_ITERS)  // 6,272,000 float4 = 100.4 MB
#define TOTAL_F4 (NROWS * (VOCAB / 4))    // 65,536,000
#define K2_F4 (TOTAL_F4 - K1_F4)          // 59,264,000

typedef __attribute__((ext_vector_type(8))) short bf16x8;
typedef __attribute__((ext_vector_type(4))) float f32x4;
typedef float f4nt __attribute__((ext_vector_type(4)));

// Monotone order-preserving f32 -> u32 (equal floats -> equal keys).
__device__ __forceinline__ unsigned enc_f32(float f) {
    unsigned u = __float_as_uint(f);
    return (u & 0x80000000u) ? ~u : (u | 0x80000000u);
}
__device__ __forceinline__ float dec_f32(unsigned e) {
    unsigned u = (e & 0x80000000u) ? (e & 0x7fffffffu) : ~e;
    return __uint_as_float(u);
}
// f32 -> bf16 round-to-nearest-even (inputs Gaussian: no NaN/Inf).
__device__ __forceinline__ unsigned short f2bf(float f) {
    unsigned u = __float_as_uint(f);
    return (unsigned short)((u + 0x7fffu + ((u >> 16) & 1u)) >> 16);
}

// ---- k1: setup (125 blocks) fused with first 100.4 MB of zero-stream ----
// Setup math identical to rounds 1-7 (exact path unchanged).
__global__ __launch_bounds__(256) void k1_kernel(
    const float* __restrict__ x, const float* __restrict__ W,
    unsigned short* __restrict__ A16, unsigned short* __restrict__ WB16,
    float* __restrict__ invn, float* __restrict__ normA,
    float4* __restrict__ out4)
{
    const int bx = blockIdx.x;
    if (bx >= K1_SETUP) {
        const int zid = bx - K1_SETUP;
        const f4nt z = {0.f, 0.f, 0.f, 0.f};
        float4* p = out4 + (size_t)zid * 256 + threadIdx.x;
        #pragma unroll 4
        for (int j = 0; j < K1_ITERS; ++j)
            __builtin_nontemporal_store(z, (f4nt*)(p + (size_t)j * (K1_ZERO * 256)));
        return;
    }
    int i = bx * 256 + threadIdx.x;
    if (i < VOCAB) {
        const float4* w4 = (const float4*)(W + (size_t)i * EMB);
        float4 buf[16];
        float s = 0.f;
        #pragma unroll
        for (int q = 0; q < 16; ++q) {
            float4 w = w4[q]; buf[q] = w;
            s += w.x * w.x + w.y * w.y + w.z * w.z + w.w * w.w;
        }
        float inv = 1.0f / sqrtf(s);
        invn[i] = inv;
        ushort4* dst = (ushort4*)(WB16 + (size_t)i * EMB);
        #pragma unroll
        for (int q = 0; q < 16; ++q) {
            float4 w = buf[q];
            ushort4 u;
            u.x = f2bf(w.x * inv); u.y = f2bf(w.y * inv);
            u.z = f2bf(w.z * inv); u.w = f2bf(w.w * inv);
            dst[q] = u;
        }
    }
    if (i < NROWS) {
        const float4* a4 = (const float4*)(x + (size_t)i * EMB);
        float4 buf[16];
        float s = 0.f;
        #pragma unroll
        for (int q = 0; q < 16; ++q) {
            float4 a = a4[q]; buf[q] = a;
            s += a.x * a.x + a.y * a.y + a.z * a.z + a.w * a.w;
        }
        normA[i] = sqrtf(s);
        ushort4* dst = (ushort4*)(A16 + (size_t)i * EMB);
        #pragma unroll
        for (int q = 0; q < 16; ++q) {
            float4 a = buf[q];
            ushort4 u;
            u.x = f2bf(a.x); u.y = f2bf(a.y); u.z = f2bf(a.z); u.w = f2bf(a.w);
            dst[q] = u;
        }
    }
}

// 4-tile (64-col) group load / compute helpers for the pipelined K-loop.
#define LOAD_GROUP(buf, base)                                            \
    {                                                                    \
        _Pragma("unroll")                                                \
        for (int tt = 0; tt < 4; ++tt) {                                 \
            buf[tt][0] = *(const bf16x8*)((base) + tt * 16 * EMB);       \
            buf[tt][1] = *(const bf16x8*)((base) + tt * 16 * EMB + 32);  \
        }                                                                \
    }
#define COMPUTE_GROUP(buf)                                               \
    {                                                                    \
        _Pragma("unroll")                                                \
        for (int tt = 0; tt < 4; ++tt) {                                 \
            _Pragma("unroll")                                            \
            for (int r = 0; r < 4; ++r) {                                \
                f32x4 acc = {0.f, 0.f, 0.f, 0.f};                        \
                acc = __builtin_amdgcn_mfma_f32_16x16x32_bf16(           \
                    a[r][0], buf[tt][0], acc, 0, 0, 0);                  \
                acc = __builtin_amdgcn_mfma_f32_16x16x32_bf16(           \
                    a[r][1], buf[tt][1], acc, 0, 0, 0);                  \
                _Pragma("unroll")                                        \
                for (int j = 0; j < 4; ++j)                              \
                    best[r][j] = fmaxf(best[r][j], acc[j]);              \
            }                                                            \
        }                                                                \
    }
#define STORE_SUB(sub)                                                   \
    {                                                                    \
        _Pragma("unroll")                                                \
        for (int r = 0; r < 4; ++r) {                                    \
            _Pragma("unroll")                                            \
            for (int j = 0; j < 4; ++j) {                                \
                float v = best[r][j];                                    \
                v = fmaxf(v, __shfl_xor(v, 1));                          \
                v = fmaxf(v, __shfl_xor(v, 2));                          \
                v = fmaxf(v, __shfl_xor(v, 4));                          \
                v = fmaxf(v, __shfl_xor(v, 8));                          \
                if (lr == 0)                                             \
                    pval[(size_t)(m0 + r * 16 + lg * 4 + j) * SUBPAD +   \
                         (sub)] = (unsigned short)(enc_f32(v) >> 16);    \
                best[r][j] = -3e38f;                                     \
            }                                                            \
        }                                                                \
    }

// ---- k2: 1600 compute blocks (r6 geometry: 256 rows x 640 cols each) with
//      4-tile register double-buffered B, interleaved 25:32 with 2048 zero
//      blocks streaming the remaining 948 MB ----
// Batched loads: 8 back-to-back b128 loads per 64-col group -> one
// congested-latency window amortized over 32 MFMAs (r7 post-mortem: 1-deep
// single-tile prefetch exposed ~2000 cyc/iter under write saturation).
__global__ __launch_bounds__(256) void k2_kernel(
    const unsigned short* __restrict__ A16,
    const unsigned short* __restrict__ WB16,
    unsigned short* __restrict__ pval, float4* __restrict__ out4)
{
    const int bx = blockIdx.x;
    const int pat = bx / PAT, off = bx - pat * PAT;

    if (off >= 25) {
        // zero block: grid-stride NT stores over [K1_F4, TOTAL_F4)
        const int zid = pat * 32 + (off - 25);          // 0..2047
        const f4nt z = {0.f, 0.f, 0.f, 0.f};
        float4* base = out4 + K1_F4;
        unsigned i = (unsigned)zid * 256u + threadIdx.x;
        const unsigned stride = (unsigned)NZ2 * 256u;
        for (; i < (unsigned)K2_F4; i += stride)
            __builtin_nontemporal_store(z, (f4nt*)(base + i));
        return;
    }

    // ---- compute block (r6 mapping: cid = rowblk + 32*chunk) ----
    const int cid = pat * 25 + off;                     // 0..1599
    const int rowblk = cid & 31, chunk = cid >> 5;      // 32 rowblks x 50 chunks
    const int lane = threadIdx.x & 63, wid = threadIdx.x >> 6;
    const int lr = lane & 15, lg = lane >> 4;
    const int m0 = rowblk * 256 + wid * 64;
    const int n0 = chunk * 640;

    bf16x8 a[4][2];
    #pragma unroll
    for (int r = 0; r < 4; ++r)
        #pragma unroll
        for (int kk = 0; kk < 2; ++kk)
            a[r][kk] = *(const bf16x8*)(A16 + (size_t)(m0 + r * 16 + lr) * EMB + kk * 32 + lg * 8);

    float best[4][4];
    #pragma unroll
    for (int r = 0; r < 4; ++r)
        #pragma unroll
        for (int j = 0; j < 4; ++j) best[r][j] = -3e38f;

    // 10 groups of 64 cols; ping-pong register buffers cb/nb.
    // Final prefetch overruns <=8KB past WB16 into A16: harmless, discarded.
    const unsigned short* wb = WB16 + (size_t)(n0 + lr) * EMB + lg * 8;
    bf16x8 cb[4][2], nb[4][2];
    LOAD_GROUP(cb, wb);
    #pragma unroll
    for (int gp = 0; gp < 5; ++gp) {
        LOAD_GROUP(nb, wb + 64 * EMB);
        COMPUTE_GROUP(cb);
        STORE_SUB(chunk * 10 + gp * 2);
        wb += 64 * EMB;
        LOAD_GROUP(cb, wb + 64 * EMB);
        COMPUTE_GROUP(nb);
        STORE_SUB(chunk * 10 + gp * 2 + 1);
        wb += 64 * EMB;
    }
}

// ---- finalize: per-row select + exact rescore + scatter (identical r6-r7) ----
// thr = max_approx - 0.009*|A| (2*2^-8*|A| bound + 15% slack, proven r3-r7).
// u16 compare (val+1)<<16 > thr_enc never false-prunes a truncated max.
__global__ __launch_bounds__(64) void finalize_kernel(
    const float* __restrict__ x, const float* __restrict__ W,
    const float* __restrict__ invn, const unsigned short* __restrict__ pval,
    const float* __restrict__ normA, float* __restrict__ out)
{
    const int row = blockIdx.x;
    const int lane = threadIdx.x;
    __shared__ float xs[EMB];
    xs[lane] = x[(size_t)row * EMB + lane];

    const unsigned short* pr = pval + (size_t)row * SUBPAD + lane * 8;
    ushort4 v0 = *(const ushort4*)(pr);
    ushort4 v1 = *(const ushort4*)(pr + 4);
    unsigned short vals[8] = {v0.x, v0.y, v0.z, v0.w, v1.x, v1.y, v1.z, v1.w};

    unsigned mx = 0;
    #pragma unroll
    for (int k = 0; k < 8; ++k)
        if (lane * 8 + k < NSUB) mx = mx > (unsigned)vals[k] ? mx : (unsigned)vals[k];
    #pragma unroll
    for (int off = 1; off < 64; off <<= 1) {
        unsigned o = __shfl_xor(mx, off);
        mx = mx > o ? mx : o;
    }
    float thr = dec_f32(mx << 16) - 0.009f * normA[row];
    unsigned thr_enc = enc_f32(thr);

    __syncthreads();
    const float4* xs4 = (const float4*)xs;
    unsigned long long best = 0ull;

    #pragma unroll
    for (int k = 0; k < 8; ++k) {
        int sub = lane * 8 + k;
        bool c = (sub < NSUB) && ((((unsigned)vals[k] + 1u) << 16) > thr_enc);
        unsigned long long m = __ballot(c);
        while (m) {   // ~1.4 survivors/row on average
            int src = __ffsll((long long)m) - 1;
            m &= m - 1;
            unsigned v = ((unsigned)(src * 8 + k)) * 64u + (unsigned)lane;
            const float4* w4 = (const float4*)(W + (size_t)v * EMB);
            float p0 = 0.f, p1 = 0.f, p2 = 0.f, p3 = 0.f;
            #pragma unroll
            for (int q = 0; q < 16; ++q) {
                float4 aa = xs4[q]; float4 ww = w4[q];
                p0 = fmaf(aa.x, ww.x, p0);
                p1 = fmaf(aa.y, ww.y, p1);
                p2 = fmaf(aa.z, ww.z, p2);
                p3 = fmaf(aa.w, ww.w, p3);
            }
            float s = ((p0 + p1) + (p2 + p3)) * invn[v];
            // larger sim wins; equal sim -> larger ~v = smaller v (numpy tie-break)
            unsigned long long kk =
                ((unsigned long long)enc_f32(s) << 32) | (unsigned)(~v);
            best = best > kk ? best : kk;
        }
    }
    #pragma unroll
    for (int off = 1; off < 64; off <<= 1) {
        unsigned long long o = __shfl_xor(best, off);
        best = best > o ? best : o;
    }
    if (lane == 0)
        out[(size_t)row * VOCAB + (size_t)(unsigned)(~(unsigned)best)] = 1.0f;
}

extern "C" void kernel_launch(void* const* d_in, const int* in_sizes, int n_in,
                              void* d_out, int out_size, void* d_ws, size_t ws_size,
                              hipStream_t stream) {
    const float* x = (const float*)d_in[0];   // [2,4096,64]
    const float* W = (const float*)d_in[1];   // [32000,64]
    float* out = (float*)d_out;

    char* ws = (char*)d_ws;
    unsigned short* WB16 = (unsigned short*)(ws);                 // 4,096,000
    unsigned short* A16  = (unsigned short*)(ws + 4096000);       // 1,048,576
    float* invn          = (float*)(ws + 5144576);                //   128,000
    float* normA         = (float*)(ws + 5272576);                //    32,768
    unsigned short* pval = (unsigned short*)(ws + 5305344);       // 8,388,608
    // total ws use: 13,693,952 B

    k1_kernel<<<dim3(K1_SETUP + K1_ZERO), dim3(256), 0, stream>>>(
        x, W, A16, WB16, invn, normA, (float4*)out);

    k2_kernel<<<dim3(K2_BLOCKS), dim3(256), 0, stream>>>(
        A16, WB16, pval, (float4*)out);

    finalize_kernel<<<dim3(NROWS), dim3(64), 0, stream>>>(
        x, W, invn, pval, normA, out);
}